// Round 1
// baseline (127.223 us; speedup 1.0000x reference)
//
#include <hip/hip_runtime.h>

// Fused Bahdanau context-attention pooling, MI355X (gfx950).
// Plan:
//   K1 prep    : q = query@Wq^T (f32), Wk -> bf16 copy in ws, mask-layout detect flag
//   K2 main    : per (b, 32-row s-chunk): kv->LDS bf16, k = kv@Wk^T via
//                mfma_f32_16x16x32_bf16, scores = sum_a tanh(q+k)*Ws, mask,
//                chunk-local online softmax (m, d) + partial context; single kv pass.
//   K3 combine : per b: global M, D from chunk partials; context = sum scaled
//                partials / D; weights = exp(score - M)/D.

typedef __attribute__((ext_vector_type(8))) short short8;
typedef __attribute__((ext_vector_type(4))) float f32x4;

#define S_LEN 4096
#define BATCH 32
#define KVD 512
#define AD 128
#define SCHN 32
#define CHUNKS_PER_B (S_LEN / SCHN)    // 128
#define NCHUNK (BATCH * CHUNKS_PER_B)  // 4096

// ws byte offsets
#define FLAG_OFF   0
#define Q_OFF      1024
#define WK_OFF     17408
#define SCORES_OFF 148480
#define MD_OFF     672768
#define CTXP_OFF   705536

__device__ __forceinline__ unsigned short f2bf(float f) {
  unsigned int u = __float_as_uint(f);
  u = (u + 0x7FFFu + ((u >> 16) & 1u)) >> 16;  // round-to-nearest-even
  return (unsigned short)u;
}
__device__ __forceinline__ float bf2f(unsigned short h) {
  return __uint_as_float(((unsigned int)h) << 16);
}
__device__ __forceinline__ float tanh_fast(float x) {
  // exp overflow -> inf -> 1.0; underflow -> 0 -> -1.0 : correct saturation
  return 1.0f - 2.0f / (1.0f + __expf(2.0f * x));
}

__global__ __launch_bounds__(256) void prep_kernel(
    const float* __restrict__ query, const float* __restrict__ Wq,
    const float* __restrict__ Wk, const void* __restrict__ maskp,
    float* __restrict__ qws, unsigned short* __restrict__ wkb,
    int* __restrict__ flagp) {
  int blk = blockIdx.x, t = threadIdx.x;
  if (blk < 32) {
    // q[blk][a] = sum_k query[blk][k] * Wq[a][k]
    __shared__ float qrow[KVD];
    qrow[t] = query[blk * KVD + t];
    qrow[t + 256] = query[blk * KVD + t + 256];
    __syncthreads();
    int a = t >> 1, half = t & 1;
    const float4* wq4 = (const float4*)(Wq + (size_t)a * KVD + half * 256);
    const float4* qr4 = (const float4*)(qrow + half * 256);
    float s = 0.f;
#pragma unroll 8
    for (int i = 0; i < 64; ++i) {
      float4 wv = wq4[i], qv = qr4[i];
      s += wv.x * qv.x + wv.y * qv.y + wv.z * qv.z + wv.w * qv.w;
    }
    s += __shfl_xor(s, 1);
    if (half == 0) qws[blk * AD + a] = s;
  } else if (blk < 40) {
    // Wk f32 -> bf16 (AD*KVD = 65536 elems = 16384 float4s, 8 blocks)
    int j = blk - 32;
    const float4* src = (const float4*)Wk;
#pragma unroll 4
    for (int i = 0; i < 8; ++i) {
      int idx4 = j * 2048 + i * 256 + t;
      float4 v = src[idx4];
      ushort4 o;
      o.x = f2bf(v.x); o.y = f2bf(v.y); o.z = f2bf(v.z); o.w = f2bf(v.w);
      ((ushort4*)wkb)[idx4] = o;
    }
  } else {
    // mask layout detection: int32 0/1 words vs packed bool bytes
    __shared__ int okv;
    if (t == 0) okv = 1;
    __syncthreads();
    if (t < 128) {
      int wv = ((const int*)maskp)[t];
      if (!(wv == 0 || wv == 1)) okv = 0;  // benign race, all write 0
    }
    __syncthreads();
    if (t == 0) flagp[0] = okv;  // 1 = int32 layout, 0 = byte layout
  }
}

__global__ __launch_bounds__(256) void main_kernel(
    const float* __restrict__ kv, const void* __restrict__ maskp,
    const float* __restrict__ Ws, const float* __restrict__ qws,
    const unsigned short* __restrict__ wkb, const int* __restrict__ flagp,
    float* __restrict__ scores, float* __restrict__ md,
    float* __restrict__ ctxp) {
  int blk = blockIdx.x, t = threadIdx.x;
  int b = blk >> 7, chunk = blk & 127;
  int s0 = chunk * SCHN;

  __shared__ unsigned short kvb[SCHN][520];  // bf16 kv tile, padded pitch
  __shared__ float qs[AD], wss[AD];
  __shared__ float scp[4][SCHN];
  __shared__ float esc[SCHN];

  if (t < AD) { qs[t] = qws[b * AD + t]; wss[t] = Ws[t]; }

  // stage kv chunk (32x512 f32, contiguous 64KB) -> LDS bf16
  const float4* kvv = (const float4*)(kv + (size_t)b * S_LEN * KVD + (size_t)s0 * KVD);
#pragma unroll 4
  for (int i = 0; i < 16; ++i) {
    int idx4 = t + 256 * i;
    float4 v = kvv[idx4];
    int c4 = idx4 << 2;
    int r = c4 >> 9, c = c4 & 511;
    uint2 pk;
    pk.x = (unsigned)f2bf(v.x) | ((unsigned)f2bf(v.y) << 16);
    pk.y = (unsigned)f2bf(v.z) | ((unsigned)f2bf(v.w) << 16);
    *(uint2*)&kvb[r][c] = pk;
  }
  __syncthreads();

  // ---- projection: C[s(32)][a(128)] = kv @ Wk^T via 16x16x32 bf16 MFMA ----
  int lane = t & 63, wave = t >> 6;
  int lr = lane & 15, lg = lane >> 4;
  int a0 = wave * 32;  // each wave owns 32 a-columns (2 N-tiles)
  f32x4 acc[2][2];
#pragma unroll
  for (int mi = 0; mi < 2; ++mi)
#pragma unroll
    for (int ni = 0; ni < 2; ++ni) acc[mi][ni] = (f32x4)0.f;

#pragma unroll 4
  for (int kk = 0; kk < KVD / 32; ++kk) {
    int kb = kk * 32 + lg * 8;
    short8 af0 = *(const short8*)&kvb[lr][kb];
    short8 af1 = *(const short8*)&kvb[16 + lr][kb];
    short8 bf0 = *(const short8*)(wkb + (size_t)(a0 + lr) * KVD + kb);
    short8 bf1 = *(const short8*)(wkb + (size_t)(a0 + 16 + lr) * KVD + kb);
    acc[0][0] = __builtin_amdgcn_mfma_f32_16x16x32_bf16(af0, bf0, acc[0][0], 0, 0, 0);
    acc[1][0] = __builtin_amdgcn_mfma_f32_16x16x32_bf16(af1, bf0, acc[1][0], 0, 0, 0);
    acc[0][1] = __builtin_amdgcn_mfma_f32_16x16x32_bf16(af0, bf1, acc[0][1], 0, 0, 0);
    acc[1][1] = __builtin_amdgcn_mfma_f32_16x16x32_bf16(af1, bf1, acc[1][1], 0, 0, 0);
  }

  // ---- scores: sum_a tanh(q[a] + k[s][a]) * Ws[a] ----
  // D layout: col a = a0 + ni*16 + (lane&15), row s = mi*16 + 4*(lane>>4) + reg
#pragma unroll
  for (int mi = 0; mi < 2; ++mi) {
#pragma unroll
    for (int reg = 0; reg < 4; ++reg) {
      float v = 0.f;
#pragma unroll
      for (int ni = 0; ni < 2; ++ni) {
        int a = a0 + ni * 16 + lr;
        float x = qs[a] + acc[mi][ni][reg];
        v += tanh_fast(x) * wss[a];
      }
      v += __shfl_xor(v, 1);
      v += __shfl_xor(v, 2);
      v += __shfl_xor(v, 4);
      v += __shfl_xor(v, 8);
      if (lr == 0) scp[wave][mi * 16 + lg * 4 + reg] = v;
    }
  }
  __syncthreads();

  // ---- chunk-local masked online softmax ----
  if (t < SCHN) {
    float sm = scp[0][t] + scp[1][t] + scp[2][t] + scp[3][t];
    int gs = s0 + t;
    int flag = flagp[0];
    int mk = flag ? ((const int*)maskp)[b * S_LEN + gs]
                  : (int)((const unsigned char*)maskp)[b * S_LEN + gs];
    float score = mk ? sm : -INFINITY;
    scores[b * S_LEN + gs] = score;
    float m = score;
    m = fmaxf(m, __shfl_xor(m, 16));
    m = fmaxf(m, __shfl_xor(m, 8));
    m = fmaxf(m, __shfl_xor(m, 4));
    m = fmaxf(m, __shfl_xor(m, 2));
    m = fmaxf(m, __shfl_xor(m, 1));
    float e = (score == -INFINITY) ? 0.f : __expf(score - m);
    float d = e;
    d += __shfl_xor(d, 16);
    d += __shfl_xor(d, 8);
    d += __shfl_xor(d, 4);
    d += __shfl_xor(d, 2);
    d += __shfl_xor(d, 1);
    esc[t] = e;
    if (t == 0) { md[blk * 2] = m; md[blk * 2 + 1] = d; }
  }
  __syncthreads();

  // ---- partial context: ctx_j[k] = sum_s e_s * kv[s][k]  (k split 2/thread) ----
  {
    float c0 = 0.f, c1 = 0.f;
#pragma unroll 4
    for (int s = 0; s < SCHN; ++s) {
      float e = esc[s];
      unsigned int u = *(const unsigned int*)&kvb[s][2 * t];
      c0 += e * bf2f((unsigned short)u);
      c1 += e * bf2f((unsigned short)(u >> 16));
    }
    ctxp[(size_t)blk * KVD + 2 * t] = c0;
    ctxp[(size_t)blk * KVD + 2 * t + 1] = c1;
  }
}

__global__ __launch_bounds__(512) void combine_kernel(
    const float* __restrict__ md, const float* __restrict__ ctxp,
    const float* __restrict__ scores, float* __restrict__ out) {
  int b = blockIdx.x, t = threadIdx.x;
  __shared__ float mv[CHUNKS_PER_B], dv[CHUNKS_PER_B], scl[CHUNKS_PER_B];
  __shared__ float Msh, Dsh;
  if (t < CHUNKS_PER_B) {
    mv[t] = md[(b * CHUNKS_PER_B + t) * 2];
    dv[t] = md[(b * CHUNKS_PER_B + t) * 2 + 1];
  }
  __syncthreads();
  if (t < 64) {
    float m = fmaxf(mv[t], mv[t + 64]);
    m = fmaxf(m, __shfl_xor(m, 32));
    m = fmaxf(m, __shfl_xor(m, 16));
    m = fmaxf(m, __shfl_xor(m, 8));
    m = fmaxf(m, __shfl_xor(m, 4));
    m = fmaxf(m, __shfl_xor(m, 2));
    m = fmaxf(m, __shfl_xor(m, 1));
    if (t == 0) Msh = m;
  }
  __syncthreads();
  float M = Msh;
  if (t < CHUNKS_PER_B) scl[t] = (dv[t] > 0.f) ? __expf(mv[t] - M) : 0.f;
  __syncthreads();
  if (t < 64) {
    float d = scl[t] * dv[t] + scl[t + 64] * dv[t + 64];
    d += __shfl_xor(d, 32);
    d += __shfl_xor(d, 16);
    d += __shfl_xor(d, 8);
    d += __shfl_xor(d, 4);
    d += __shfl_xor(d, 2);
    d += __shfl_xor(d, 1);
    if (t == 0) Dsh = d;
  }
  __syncthreads();
  float invD = 1.f / Dsh;
  // context
  for (int c = t; c < KVD; c += 512) {
    float sum = 0.f;
#pragma unroll 4
    for (int j = 0; j < CHUNKS_PER_B; ++j)
      sum += scl[j] * ctxp[(size_t)(b * CHUNKS_PER_B + j) * KVD + c];
    out[b * KVD + c] = sum * invD;
  }
  // weights
  for (int s = t; s < S_LEN; s += 512) {
    float sc = scores[b * S_LEN + s];
    out[BATCH * KVD + b * S_LEN + s] = __expf(sc - M) * invD;  // -inf -> 0
  }
}

extern "C" void kernel_launch(void* const* d_in, const int* in_sizes, int n_in,
                              void* d_out, int out_size, void* d_ws, size_t ws_size,
                              hipStream_t stream) {
  const float* query = (const float*)d_in[0];
  const float* kv    = (const float*)d_in[1];
  const void*  maskp = d_in[2];
  const float* Wq    = (const float*)d_in[3];
  const float* Wk    = (const float*)d_in[4];
  const float* Ws    = (const float*)d_in[5];
  float* out = (float*)d_out;
  char* w = (char*)d_ws;
  int* flagp = (int*)(w + FLAG_OFF);
  float* qws = (float*)(w + Q_OFF);
  unsigned short* wkb = (unsigned short*)(w + WK_OFF);
  float* scores = (float*)(w + SCORES_OFF);
  float* md = (float*)(w + MD_OFF);
  float* ctxp = (float*)(w + CTXP_OFF);

  prep_kernel<<<41, 256, 0, stream>>>(query, Wq, Wk, maskp, qws, wkb, flagp);
  main_kernel<<<NCHUNK, 256, 0, stream>>>(kv, maskp, Ws, qws, wkb, flagp,
                                          scores, md, ctxp);
  combine_kernel<<<BATCH, 512, 0, stream>>>(md, ctxp, scores, out);
}